// Round 4
// baseline (281.020 us; speedup 1.0000x reference)
//
#include <hip/hip_runtime.h>

// SE_loss_w_threshold: h,v (8,16384,128) fp32, N scalar.
// out[0]=mean(Rp), out[1..8]=R_per_user_p, out[9]=sum(R_per_user_p)
//
// v5 = v4's half-k staging + 2x occupancy, delivered safely:
//   v4 post-mortem: __launch_bounds__(512,8) made the allocator target a
//   32-VGPR budget (VGPR_Count=32) -> every staging float4 spilled to
//   scratch (WRITE_SIZE 247 MB, FETCH 251 MB, 179us). But occupancy DID
//   reach 71%, confirming the mechanism: v1/v3's grid (1024x4 waves) only
//   ever offered 16 waves/CU; the latency-bound stall needs ~32.
//   Fix: 256-thread blocks, 2048 blocks, IT=2. __launch_bounds__(256,8)
//   yields a 64-VGPR cap under either interpretation of arg2 (8 waves/EU
//   or 8 blocks/CU -> same 2048 threads/CU). Live set ~48 regs (< v3's
//   52 which fit) -> no spills expected. LDS 18.6KB/block -> 8 blocks/CU.
//   Bank layout RS_=36: writes conflict-free, h-reads broadcast, v-reads
//   2-way (free, m136).
// A-matrix k-order (0..63 ascending) and reduction trees identical to
// v1/v4 => same numerics (v4 passed absmax 0.0).

constexpr int U_    = 8;
constexpr int B_    = 16384;
constexpr int NT_   = 128;
constexpr int NBLK_ = 2048;
constexpr int WPB_  = 4;              // waves per block (256 threads)
constexpr int TW_   = NBLK_ * WPB_;   // 8192 waves
constexpr int IT_   = B_ / TW_;       // 2 batches per wave
constexpr int RS_   = 36;             // LDS plane-row stride (floats), 16B-aligned
constexpr float T_THRESH = 0.3f;
constexpr float LOG2_10  = 3.3219280948873623f;

__device__ __forceinline__ float waveReduceSum(float v) {
    #pragma unroll
    for (int m = 1; m < 64; m <<= 1) v += __shfl_xor(v, m, 64);
    return v;
}

__device__ __forceinline__ float hw_log2(float x) { return __builtin_amdgcn_logf(x); }
__device__ __forceinline__ float hw_exp2(float x) { return __builtin_amdgcn_exp2f(x); }

__global__ __launch_bounds__(256, 8) void se_main(const float* __restrict__ h,
                                                  const float* __restrict__ vv,
                                                  const float* __restrict__ Np,
                                                  float* __restrict__ partial) {
    // Per-wave PRIVATE half-k tiles: [16 plane-rows][RS_] per array.
    // plane-row = 2*user + {0:re,1:im}; 32 floats used + 4 pad.
    __shared__ float lds[WPB_][2][16 * RS_];
    __shared__ float red_f[WPB_];
    __shared__ float red_R[WPB_][U_];

    const int tid  = threadIdx.x;
    const int wave = tid >> 6;
    const int lane = tid & 63;
    const int ui   = lane >> 3;   // user i (row of A); also staging row
    const int uj   = lane & 7;    // user j (col of A); also staging float4-col
    const float Nval = Np[0];

    float* hb = lds[wave][0];
    float* vb = lds[wave][1];

    const int gwave = blockIdx.x * WPB_ + wave;

    // Per-lane global row base for staging: row = ui, float4-col = uj.
    const float* hrb = h  + (size_t)ui * ((size_t)B_ * NT_) + uj * 4;
    const float* vrb = vv + (size_t)ui * ((size_t)B_ * NT_) + uj * 4;

    float lane_sumR = 0.0f;
    float lane_sumf = 0.0f;

    float4 rh0, rh1, rv0, rv1;

    // ---- prologue: phase 0 = (batch gwave, k-half 0) ----
    {
        const int off = gwave * NT_;                  // x=0: re at [0,32), im at [64,96)
        rh0 = *reinterpret_cast<const float4*>(hrb + off);
        rh1 = *reinterpret_cast<const float4*>(hrb + off + 64);
        rv0 = *reinterpret_cast<const float4*>(vrb + off);
        rv1 = *reinterpret_cast<const float4*>(vrb + off + 64);
    }

    #pragma unroll
    for (int it = 0; it < IT_; ++it) {
        float nsq = 0.0f, are = 0.0f, aim = 0.0f;
        #pragma unroll
        for (int x = 0; x < 2; ++x) {
            // ---- drain regs -> LDS half-tile ----
            *reinterpret_cast<float4*>(&hb[(2 * ui + 0) * RS_ + uj * 4]) = rh0;
            *reinterpret_cast<float4*>(&hb[(2 * ui + 1) * RS_ + uj * 4]) = rh1;
            *reinterpret_cast<float4*>(&vb[(2 * ui + 0) * RS_ + uj * 4]) = rv0;
            *reinterpret_cast<float4*>(&vb[(2 * ui + 1) * RS_ + uj * 4]) = rv1;
            nsq += rv0.x * rv0.x + rv0.y * rv0.y + rv0.z * rv0.z + rv0.w * rv0.w
                 + rv1.x * rv1.x + rv1.y * rv1.y + rv1.z * rv1.z + rv1.w * rv1.w;

            // ---- prefetch next phase (next k-half or next batch) ----
            const int np = it * 2 + x + 1;
            if (np < 2 * IT_) {
                const int nb  = gwave + (np >> 1) * TW_;
                const int nx  = np & 1;
                const int off = nb * NT_ + nx * 32;
                rh0 = *reinterpret_cast<const float4*>(hrb + off);
                rh1 = *reinterpret_cast<const float4*>(hrb + off + 64);
                rv0 = *reinterpret_cast<const float4*>(vrb + off);
                rv1 = *reinterpret_cast<const float4*>(vrb + off + 64);
            }

            // ---- A[i][j] partial over this k-half (global k = x*32 + ks, ascending) ----
            const float* hre = &hb[(2 * ui) * RS_];
            const float* him = hre + RS_;
            const float* vre = &vb[(2 * uj) * RS_];
            const float* vim = vre + RS_;
            #pragma unroll
            for (int ks = 0; ks < 32; ks += 4) {
                const float4 hr = *reinterpret_cast<const float4*>(hre + ks);
                const float4 hi = *reinterpret_cast<const float4*>(him + ks);
                const float4 vr = *reinterpret_cast<const float4*>(vre + ks);
                const float4 vi = *reinterpret_cast<const float4*>(vim + ks);
                are += hr.x * vr.x + hi.x * vi.x;
                aim += hi.x * vr.x - hr.x * vi.x;
                are += hr.y * vr.y + hi.y * vi.y;
                aim += hi.y * vr.y - hr.y * vi.y;
                are += hr.z * vr.z + hi.z * vi.z;
                aim += hi.z * vr.z - hr.z * vi.z;
                are += hr.w * vr.w + hi.w * vi.w;
                aim += hi.w * vr.w - hr.w * vi.w;
            }
        }

        // ---- finish batch (identical to v1) ----
        const float normsq = waveReduceSum(nsq);
        const float Iall = are * are + aim * aim;

        const float diag = __shfl(Iall, ui * 9, 64);
        float rowsum = Iall;
        rowsum += __shfl_xor(rowsum, 1, 64);
        rowsum += __shfl_xor(rowsum, 2, 64);
        rowsum += __shfl_xor(rowsum, 4, 64);

        const float Ip   = rowsum - diag;
        const float S    = (8.0f / normsq) * diag;
        const float SINR = S / (Ip + Nval);
        const float R    = hw_log2(1.0f + SINR);

        lane_sumR += R;
        lane_sumf += hw_exp2((T_THRESH - R) * LOG2_10) - R;
    }

    // ---- block-level reduction ----
    const float wf = waveReduceSum(lane_sumf) * 0.125f;  // each user counted 8x
    if (lane == 0) red_f[wave] = wf;
    if (uj == 0)   red_R[wave][ui] = lane_sumR;
    __syncthreads();

    if (tid < U_) {
        float s = 0.0f;
        #pragma unroll
        for (int w = 0; w < WPB_; ++w) s += red_R[w][tid];
        partial[blockIdx.x * 9 + 1 + tid] = s;
    } else if (tid == U_) {
        float s = 0.0f;
        #pragma unroll
        for (int w = 0; w < WPB_; ++w) s += red_f[w];
        partial[blockIdx.x * 9] = s;
    }
}

__global__ __launch_bounds__(1024) void se_final(const float* __restrict__ partial,
                                                 float* __restrict__ out) {
    // 2048 partial rows: each of 1024 threads folds 2 rows, then
    // deterministic wave trees + fixed cross-wave order (no atomics).
    __shared__ float acc[16][9];
    const int tid = threadIdx.x, w = tid >> 6, l = tid & 63;

    float v[9];
    #pragma unroll
    for (int s = 0; s < 9; ++s)
        v[s] = partial[tid * 9 + s] + partial[(tid + 1024) * 9 + s];

    #pragma unroll
    for (int s = 0; s < 9; ++s) {
        float t = v[s];
        #pragma unroll
        for (int m = 1; m < 64; m <<= 1) t += __shfl_xor(t, m, 64);
        if (l == 0) acc[w][s] = t;
    }
    __syncthreads();

    if (tid == 0) {
        float sums[9];
        #pragma unroll
        for (int s = 0; s < 9; ++s) {
            float t = acc[0][s];
            #pragma unroll
            for (int ww = 1; ww < 16; ++ww) t += acc[ww][s];
            sums[s] = t;
        }
        const float inv = 1.0f / (float)B_;
        out[0] = sums[0] * inv;          // mean(Rp)
        float tot = 0.0f;
        #pragma unroll
        for (int i = 0; i < U_; ++i) {
            const float r = sums[1 + i] * inv;
            out[1 + i] = r;              // R_per_user_p
            tot += r;
        }
        out[9] = tot;                    // sum(R_per_user_p)
    }
}

extern "C" void kernel_launch(void* const* d_in, const int* in_sizes, int n_in,
                              void* d_out, int out_size, void* d_ws, size_t ws_size,
                              hipStream_t stream) {
    const float* h  = (const float*)d_in[0];
    const float* v  = (const float*)d_in[1];
    const float* Np = (const float*)d_in[2];
    float* out      = (float*)d_out;
    float* partial  = (float*)d_ws;   // NBLK_*9 floats (73728 B), fully overwritten each call

    se_main<<<NBLK_, 256, 0, stream>>>(h, v, Np, partial);
    se_final<<<1, 1024, 0, stream>>>(partial, out);
}

// Round 5
// 205.750 us; speedup vs baseline: 1.3658x; 1.3658x over previous
//
#include <hip/hip_runtime.h>

// SE_loss_w_threshold: h,v (8,16384,128) fp32, N scalar.
// out[0]=mean(Rp), out[1..8]=R_per_user_p, out[9]=sum(R_per_user_p)
//
// v6 = v5 with __launch_bounds__(256, 4).
//   v4/v5 post-mortem: arg2=8 makes the allocator target 32 VGPRs (both
//   512- and 256-thread blocks) -> staging float4s spill to scratch
//   (WRITE_SIZE 241 MB vs 64 KB real output, se_main 179us). arg2=4
//   empirically yields 52-60 VGPRs with no spill (v1/v3).
//   launch_bounds arg2 is only the compiler's register TARGET; hardware
//   occupancy follows ACTUAL usage: <=64 VGPR allows 8 waves/SIMD (m69),
//   LDS 18.9KB/block allows 8 blocks/CU, grid 2048x256 delivers exactly
//   8 blocks/CU = 32 waves/CU — 2x v1/v3's latency-hiding capacity.
//   (v1/v3's real cap was the 1024-block grid + 34KB LDS, both fixed
//   since v5; only the register budget was broken.)
// A-matrix k-order (0..63 ascending) and reduction trees identical to
// v1/v4/v5 => same numerics (v5 passed absmax 0.0 even while spilling).

constexpr int U_    = 8;
constexpr int B_    = 16384;
constexpr int NT_   = 128;
constexpr int NBLK_ = 2048;
constexpr int WPB_  = 4;              // waves per block (256 threads)
constexpr int TW_   = NBLK_ * WPB_;   // 8192 waves
constexpr int IT_   = B_ / TW_;       // 2 batches per wave
constexpr int RS_   = 36;             // LDS plane-row stride (floats), 16B-aligned
constexpr float T_THRESH = 0.3f;
constexpr float LOG2_10  = 3.3219280948873623f;

__device__ __forceinline__ float waveReduceSum(float v) {
    #pragma unroll
    for (int m = 1; m < 64; m <<= 1) v += __shfl_xor(v, m, 64);
    return v;
}

__device__ __forceinline__ float hw_log2(float x) { return __builtin_amdgcn_logf(x); }
__device__ __forceinline__ float hw_exp2(float x) { return __builtin_amdgcn_exp2f(x); }

__global__ __launch_bounds__(256, 4) void se_main(const float* __restrict__ h,
                                                  const float* __restrict__ vv,
                                                  const float* __restrict__ Np,
                                                  float* __restrict__ partial) {
    // Per-wave PRIVATE half-k tiles: [16 plane-rows][RS_] per array.
    // plane-row = 2*user + {0:re,1:im}; 32 floats used + 4 pad.
    __shared__ float lds[WPB_][2][16 * RS_];
    __shared__ float red_f[WPB_];
    __shared__ float red_R[WPB_][U_];

    const int tid  = threadIdx.x;
    const int wave = tid >> 6;
    const int lane = tid & 63;
    const int ui   = lane >> 3;   // user i (row of A); also staging row
    const int uj   = lane & 7;    // user j (col of A); also staging float4-col
    const float Nval = Np[0];

    float* hb = lds[wave][0];
    float* vb = lds[wave][1];

    const int gwave = blockIdx.x * WPB_ + wave;

    // Per-lane global row base for staging: row = ui, float4-col = uj.
    const float* hrb = h  + (size_t)ui * ((size_t)B_ * NT_) + uj * 4;
    const float* vrb = vv + (size_t)ui * ((size_t)B_ * NT_) + uj * 4;

    float lane_sumR = 0.0f;
    float lane_sumf = 0.0f;

    float4 rh0, rh1, rv0, rv1;

    // ---- prologue: phase 0 = (batch gwave, k-half 0) ----
    {
        const int off = gwave * NT_;                  // x=0: re at [0,32), im at [64,96)
        rh0 = *reinterpret_cast<const float4*>(hrb + off);
        rh1 = *reinterpret_cast<const float4*>(hrb + off + 64);
        rv0 = *reinterpret_cast<const float4*>(vrb + off);
        rv1 = *reinterpret_cast<const float4*>(vrb + off + 64);
    }

    #pragma unroll
    for (int it = 0; it < IT_; ++it) {
        float nsq = 0.0f, are = 0.0f, aim = 0.0f;
        #pragma unroll
        for (int x = 0; x < 2; ++x) {
            // ---- drain regs -> LDS half-tile ----
            *reinterpret_cast<float4*>(&hb[(2 * ui + 0) * RS_ + uj * 4]) = rh0;
            *reinterpret_cast<float4*>(&hb[(2 * ui + 1) * RS_ + uj * 4]) = rh1;
            *reinterpret_cast<float4*>(&vb[(2 * ui + 0) * RS_ + uj * 4]) = rv0;
            *reinterpret_cast<float4*>(&vb[(2 * ui + 1) * RS_ + uj * 4]) = rv1;
            nsq += rv0.x * rv0.x + rv0.y * rv0.y + rv0.z * rv0.z + rv0.w * rv0.w
                 + rv1.x * rv1.x + rv1.y * rv1.y + rv1.z * rv1.z + rv1.w * rv1.w;

            // ---- prefetch next phase (next k-half or next batch) ----
            const int np = it * 2 + x + 1;
            if (np < 2 * IT_) {
                const int nb  = gwave + (np >> 1) * TW_;
                const int nx  = np & 1;
                const int off = nb * NT_ + nx * 32;
                rh0 = *reinterpret_cast<const float4*>(hrb + off);
                rh1 = *reinterpret_cast<const float4*>(hrb + off + 64);
                rv0 = *reinterpret_cast<const float4*>(vrb + off);
                rv1 = *reinterpret_cast<const float4*>(vrb + off + 64);
            }

            // ---- A[i][j] partial over this k-half (global k = x*32 + ks, ascending) ----
            const float* hre = &hb[(2 * ui) * RS_];
            const float* him = hre + RS_;
            const float* vre = &vb[(2 * uj) * RS_];
            const float* vim = vre + RS_;
            #pragma unroll
            for (int ks = 0; ks < 32; ks += 4) {
                const float4 hr = *reinterpret_cast<const float4*>(hre + ks);
                const float4 hi = *reinterpret_cast<const float4*>(him + ks);
                const float4 vr = *reinterpret_cast<const float4*>(vre + ks);
                const float4 vi = *reinterpret_cast<const float4*>(vim + ks);
                are += hr.x * vr.x + hi.x * vi.x;
                aim += hi.x * vr.x - hr.x * vi.x;
                are += hr.y * vr.y + hi.y * vi.y;
                aim += hi.y * vr.y - hr.y * vi.y;
                are += hr.z * vr.z + hi.z * vi.z;
                aim += hi.z * vr.z - hr.z * vi.z;
                are += hr.w * vr.w + hi.w * vi.w;
                aim += hi.w * vr.w - hr.w * vi.w;
            }
        }

        // ---- finish batch (identical to v1) ----
        const float normsq = waveReduceSum(nsq);
        const float Iall = are * are + aim * aim;

        const float diag = __shfl(Iall, ui * 9, 64);
        float rowsum = Iall;
        rowsum += __shfl_xor(rowsum, 1, 64);
        rowsum += __shfl_xor(rowsum, 2, 64);
        rowsum += __shfl_xor(rowsum, 4, 64);

        const float Ip   = rowsum - diag;
        const float S    = (8.0f / normsq) * diag;
        const float SINR = S / (Ip + Nval);
        const float R    = hw_log2(1.0f + SINR);

        lane_sumR += R;
        lane_sumf += hw_exp2((T_THRESH - R) * LOG2_10) - R;
    }

    // ---- block-level reduction ----
    const float wf = waveReduceSum(lane_sumf) * 0.125f;  // each user counted 8x
    if (lane == 0) red_f[wave] = wf;
    if (uj == 0)   red_R[wave][ui] = lane_sumR;
    __syncthreads();

    if (tid < U_) {
        float s = 0.0f;
        #pragma unroll
        for (int w = 0; w < WPB_; ++w) s += red_R[w][tid];
        partial[blockIdx.x * 9 + 1 + tid] = s;
    } else if (tid == U_) {
        float s = 0.0f;
        #pragma unroll
        for (int w = 0; w < WPB_; ++w) s += red_f[w];
        partial[blockIdx.x * 9] = s;
    }
}

__global__ __launch_bounds__(1024) void se_final(const float* __restrict__ partial,
                                                 float* __restrict__ out) {
    // 2048 partial rows: each of 1024 threads folds 2 rows, then
    // deterministic wave trees + fixed cross-wave order (no atomics).
    __shared__ float acc[16][9];
    const int tid = threadIdx.x, w = tid >> 6, l = tid & 63;

    float v[9];
    #pragma unroll
    for (int s = 0; s < 9; ++s)
        v[s] = partial[tid * 9 + s] + partial[(tid + 1024) * 9 + s];

    #pragma unroll
    for (int s = 0; s < 9; ++s) {
        float t = v[s];
        #pragma unroll
        for (int m = 1; m < 64; m <<= 1) t += __shfl_xor(t, m, 64);
        if (l == 0) acc[w][s] = t;
    }
    __syncthreads();

    if (tid == 0) {
        float sums[9];
        #pragma unroll
        for (int s = 0; s < 9; ++s) {
            float t = acc[0][s];
            #pragma unroll
            for (int ww = 1; ww < 16; ++ww) t += acc[ww][s];
            sums[s] = t;
        }
        const float inv = 1.0f / (float)B_;
        out[0] = sums[0] * inv;          // mean(Rp)
        float tot = 0.0f;
        #pragma unroll
        for (int i = 0; i < U_; ++i) {
            const float r = sums[1 + i] * inv;
            out[1 + i] = r;              // R_per_user_p
            tot += r;
        }
        out[9] = tot;                    // sum(R_per_user_p)
    }
}

extern "C" void kernel_launch(void* const* d_in, const int* in_sizes, int n_in,
                              void* d_out, int out_size, void* d_ws, size_t ws_size,
                              hipStream_t stream) {
    const float* h  = (const float*)d_in[0];
    const float* v  = (const float*)d_in[1];
    const float* Np = (const float*)d_in[2];
    float* out      = (float*)d_out;
    float* partial  = (float*)d_ws;   // NBLK_*9 floats (73728 B), fully overwritten each call

    se_main<<<NBLK_, 256, 0, stream>>>(h, v, Np, partial);
    se_final<<<1, 1024, 0, stream>>>(partial, out);
}

// Round 7
// 156.388 us; speedup vs baseline: 1.7969x; 1.3156x over previous
//
#include <hip/hip_runtime.h>

// SE_loss_w_threshold: h,v (8,16384,128) fp32, N scalar.
// out[0]=mean(Rp), out[1..8]=R_per_user_p, out[9]=sum(R_per_user_p)
//
// v7 = v6 minus the cross-phase register prefetch. (Resubmitted verbatim
// after an infra-only bench failure: "MI355X container failed twice" —
// no kernel signal to act on.)
//   v4/v5/v6 post-mortem: empirical VGPR cap = 256/arg2 on this toolchain
//   (arg2=4 -> 64). Carrying 4 staged float4s across the k-loop pushes the
//   live set past 64 -> allocator spills exactly those 16 floats per phase
//   (WRITE_SIZE 129MB = 8192 waves x 4 phases x 4KB). v3's "prefetch" only
//   fit in 52 regs because the compiler sank the loads to the use point --
//   the pipeline never existed. So: abandon intra-wave pipelining, use
//   transient staging (global->reg->LDS in the same phase, v1 dataflow) and
//   let 32 waves/CU of TLP hide the load latency instead.
//   Occupancy plumbing retained from v5/v6: 2048 blocks x 256 thr, IT=2,
//   half-k LDS tiles (18.9KB/block) -> 8 blocks/CU = 32 waves/CU, 2x v1.
//   LDS-pipe floor ~25us; HBM floor ~10.6us (overlapped).
// A-matrix k-order (0..63 ascending) and all reduction trees identical to
// v1/v4/v5/v6 => same numerics (absmax 0.0 across all prior rounds).

constexpr int U_    = 8;
constexpr int B_    = 16384;
constexpr int NT_   = 128;
constexpr int NBLK_ = 2048;
constexpr int WPB_  = 4;              // waves per block (256 threads)
constexpr int TW_   = NBLK_ * WPB_;   // 8192 waves
constexpr int IT_   = B_ / TW_;       // 2 batches per wave
constexpr int RS_   = 36;             // LDS plane-row stride (floats), 16B-aligned
constexpr float T_THRESH = 0.3f;
constexpr float LOG2_10  = 3.3219280948873623f;

__device__ __forceinline__ float waveReduceSum(float v) {
    #pragma unroll
    for (int m = 1; m < 64; m <<= 1) v += __shfl_xor(v, m, 64);
    return v;
}

__device__ __forceinline__ float hw_log2(float x) { return __builtin_amdgcn_logf(x); }
__device__ __forceinline__ float hw_exp2(float x) { return __builtin_amdgcn_exp2f(x); }

__global__ __launch_bounds__(256, 4) void se_main(const float* __restrict__ h,
                                                  const float* __restrict__ vv,
                                                  const float* __restrict__ Np,
                                                  float* __restrict__ partial) {
    // Per-wave PRIVATE half-k tiles: [16 plane-rows][RS_] per array.
    // plane-row = 2*user + {0:re,1:im}; 32 floats used + 4 pad.
    // Wave-private => no __syncthreads in the loop; same-wave ds-write ->
    // ds-read ordering is guaranteed by lgkmcnt (v1-proven pattern).
    __shared__ float lds[WPB_][2][16 * RS_];
    __shared__ float red_f[WPB_];
    __shared__ float red_R[WPB_][U_];

    const int tid  = threadIdx.x;
    const int wave = tid >> 6;
    const int lane = tid & 63;
    const int ui   = lane >> 3;   // user i (row of A); also staging row
    const int uj   = lane & 7;    // user j (col of A); also staging float4-col
    const float Nval = Np[0];

    float* hb = lds[wave][0];
    float* vb = lds[wave][1];

    const int gwave = blockIdx.x * WPB_ + wave;

    // Per-lane global row base for staging: row = ui, float4-col = uj.
    const float* hrb = h  + (size_t)ui * ((size_t)B_ * NT_) + uj * 4;
    const float* vrb = vv + (size_t)ui * ((size_t)B_ * NT_) + uj * 4;

    float lane_sumR = 0.0f;
    float lane_sumf = 0.0f;

    #pragma unroll
    for (int it = 0; it < IT_; ++it) {
        const int b = gwave + it * TW_;
        float nsq = 0.0f, are = 0.0f, aim = 0.0f;

        #pragma unroll
        for (int x = 0; x < 2; ++x) {
            // ---- transient staging: global -> reg -> LDS within this phase ----
            // x=0: re half at [0,32), im half at [64,96); x=1: [32,64)/[96,128)
            const int off = b * NT_ + x * 32;
            const float4 rh0 = *reinterpret_cast<const float4*>(hrb + off);
            const float4 rh1 = *reinterpret_cast<const float4*>(hrb + off + 64);
            const float4 rv0 = *reinterpret_cast<const float4*>(vrb + off);
            const float4 rv1 = *reinterpret_cast<const float4*>(vrb + off + 64);

            *reinterpret_cast<float4*>(&hb[(2 * ui + 0) * RS_ + uj * 4]) = rh0;
            *reinterpret_cast<float4*>(&hb[(2 * ui + 1) * RS_ + uj * 4]) = rh1;
            *reinterpret_cast<float4*>(&vb[(2 * ui + 0) * RS_ + uj * 4]) = rv0;
            *reinterpret_cast<float4*>(&vb[(2 * ui + 1) * RS_ + uj * 4]) = rv1;
            nsq += rv0.x * rv0.x + rv0.y * rv0.y + rv0.z * rv0.z + rv0.w * rv0.w
                 + rv1.x * rv1.x + rv1.y * rv1.y + rv1.z * rv1.z + rv1.w * rv1.w;

            // ---- A[i][j] partial over this k-half (global k = x*32 + ks, ascending) ----
            const float* hre = &hb[(2 * ui) * RS_];
            const float* him = hre + RS_;
            const float* vre = &vb[(2 * uj) * RS_];
            const float* vim = vre + RS_;
            #pragma unroll
            for (int ks = 0; ks < 32; ks += 4) {
                const float4 hr = *reinterpret_cast<const float4*>(hre + ks);
                const float4 hi = *reinterpret_cast<const float4*>(him + ks);
                const float4 vr = *reinterpret_cast<const float4*>(vre + ks);
                const float4 vi = *reinterpret_cast<const float4*>(vim + ks);
                are += hr.x * vr.x + hi.x * vi.x;
                aim += hi.x * vr.x - hr.x * vi.x;
                are += hr.y * vr.y + hi.y * vi.y;
                aim += hi.y * vr.y - hr.y * vi.y;
                are += hr.z * vr.z + hi.z * vi.z;
                aim += hi.z * vr.z - hr.z * vi.z;
                are += hr.w * vr.w + hi.w * vi.w;
                aim += hi.w * vr.w - hr.w * vi.w;
            }
        }

        // ---- finish batch (identical to v1) ----
        const float normsq = waveReduceSum(nsq);
        const float Iall = are * are + aim * aim;

        const float diag = __shfl(Iall, ui * 9, 64);
        float rowsum = Iall;
        rowsum += __shfl_xor(rowsum, 1, 64);
        rowsum += __shfl_xor(rowsum, 2, 64);
        rowsum += __shfl_xor(rowsum, 4, 64);

        const float Ip   = rowsum - diag;
        const float S    = (8.0f / normsq) * diag;
        const float SINR = S / (Ip + Nval);
        const float R    = hw_log2(1.0f + SINR);

        lane_sumR += R;
        lane_sumf += hw_exp2((T_THRESH - R) * LOG2_10) - R;
    }

    // ---- block-level reduction ----
    const float wf = waveReduceSum(lane_sumf) * 0.125f;  // each user counted 8x
    if (lane == 0) red_f[wave] = wf;
    if (uj == 0)   red_R[wave][ui] = lane_sumR;
    __syncthreads();

    if (tid < U_) {
        float s = 0.0f;
        #pragma unroll
        for (int w = 0; w < WPB_; ++w) s += red_R[w][tid];
        partial[blockIdx.x * 9 + 1 + tid] = s;
    } else if (tid == U_) {
        float s = 0.0f;
        #pragma unroll
        for (int w = 0; w < WPB_; ++w) s += red_f[w];
        partial[blockIdx.x * 9] = s;
    }
}

__global__ __launch_bounds__(1024) void se_final(const float* __restrict__ partial,
                                                 float* __restrict__ out) {
    // 2048 partial rows: each of 1024 threads folds 2 rows, then
    // deterministic wave trees + fixed cross-wave order (no atomics).
    __shared__ float acc[16][9];
    const int tid = threadIdx.x, w = tid >> 6, l = tid & 63;

    float v[9];
    #pragma unroll
    for (int s = 0; s < 9; ++s)
        v[s] = partial[tid * 9 + s] + partial[(tid + 1024) * 9 + s];

    #pragma unroll
    for (int s = 0; s < 9; ++s) {
        float t = v[s];
        #pragma unroll
        for (int m = 1; m < 64; m <<= 1) t += __shfl_xor(t, m, 64);
        if (l == 0) acc[w][s] = t;
    }
    __syncthreads();

    if (tid == 0) {
        float sums[9];
        #pragma unroll
        for (int s = 0; s < 9; ++s) {
            float t = acc[0][s];
            #pragma unroll
            for (int ww = 1; ww < 16; ++ww) t += acc[ww][s];
            sums[s] = t;
        }
        const float inv = 1.0f / (float)B_;
        out[0] = sums[0] * inv;          // mean(Rp)
        float tot = 0.0f;
        #pragma unroll
        for (int i = 0; i < U_; ++i) {
            const float r = sums[1 + i] * inv;
            out[1 + i] = r;              // R_per_user_p
            tot += r;
        }
        out[9] = tot;                    // sum(R_per_user_p)
    }
}

extern "C" void kernel_launch(void* const* d_in, const int* in_sizes, int n_in,
                              void* d_out, int out_size, void* d_ws, size_t ws_size,
                              hipStream_t stream) {
    const float* h  = (const float*)d_in[0];
    const float* v  = (const float*)d_in[1];
    const float* Np = (const float*)d_in[2];
    float* out      = (float*)d_out;
    float* partial  = (float*)d_ws;   // NBLK_*9 floats (73728 B), fully overwritten each call

    se_main<<<NBLK_, 256, 0, stream>>>(h, v, Np, partial);
    se_final<<<1, 1024, 0, stream>>>(partial, out);
}